// Round 1
// baseline (503.885 us; speedup 1.0000x reference)
//
#include <hip/hip_runtime.h>
#include <math.h>

#define SEQ    2048
#define DH     64
#define NBH    24        // batch*heads = 2*12
#define BT     64        // q-tile rows == k-tile rows
#define PAD    68        // LDS row stride (floats); 68%32=4 -> rotating banks
#define KTILES (SEQ / BT)

// One block per (bh, q-tile of 64 rows). 256 threads = 16x16 (tx,ty).
// Thread (tx,ty) owns S rows {ty+16i}, S cols {tx+16j}, O rows {ty+16i},
// O d-cols {4tx..4tx+3}. Stride-16 row interleave keeps LDS reads <=2-way
// bank-conflicted (free). SCALE folded into Q at stage time.
__global__ __launch_bounds__(256, 3)
void attn_fwd(const float* __restrict__ qg,
              const float* __restrict__ kg,
              const float* __restrict__ vg,
              float* __restrict__ og)
{
    __shared__ float sQ [BT][PAD];
    __shared__ float sKP[BT][PAD];   // K tile; reused as P tile after scores
    __shared__ float sV [BT][PAD];

    const int tid = threadIdx.x;
    const int tx  = tid & 15;
    const int ty  = tid >> 4;
    const int bh    = blockIdx.y;
    const int qbase = blockIdx.x * BT;

    const float* qp = qg + ((size_t)bh * SEQ + qbase) * DH;
    const float* kp = kg + (size_t)bh * SEQ * DH;
    const float* vp = vg + (size_t)bh * SEQ * DH;

    // stage Q tile, folding in softmax scale
    #pragma unroll
    for (int p = 0; p < 4; ++p) {
        int r = ty + 16 * p;
        float4 t = *(const float4*)(qp + r * DH + tx * 4);
        t.x *= 0.125f; t.y *= 0.125f; t.z *= 0.125f; t.w *= 0.125f;
        *(float4*)(&sQ[r][tx * 4]) = t;
    }

    float m_i[4], l_i[4], acc[4][4];
    #pragma unroll
    for (int i = 0; i < 4; ++i) {
        m_i[i] = -INFINITY; l_i[i] = 0.f;
        #pragma unroll
        for (int c = 0; c < 4; ++c) acc[i][c] = 0.f;
    }

    for (int kt = 0; kt < KTILES; ++kt) {
        __syncthreads();   // prev-iter P/V reads done (and Q staged, iter 0)
        const float* kpt = kp + (size_t)(kt * BT) * DH;
        const float* vpt = vp + (size_t)(kt * BT) * DH;
        #pragma unroll
        for (int p = 0; p < 4; ++p) {
            int r = ty + 16 * p;
            *(float4*)(&sKP[r][tx*4]) = *(const float4*)(kpt + r * DH + tx * 4);
            *(float4*)(&sV [r][tx*4]) = *(const float4*)(vpt + r * DH + tx * 4);
        }
        __syncthreads();

        // ---- S = (Q*scale) @ K^T, 4x4 register tile ----
        float s[4][4];
        #pragma unroll
        for (int i = 0; i < 4; ++i)
            #pragma unroll
            for (int j = 0; j < 4; ++j) s[i][j] = 0.f;

        #pragma unroll 2
        for (int d0 = 0; d0 < DH; d0 += 4) {
            float4 qv[4], kv[4];
            #pragma unroll
            for (int i = 0; i < 4; ++i) qv[i] = *(const float4*)(&sQ[ty + 16*i][d0]);
            #pragma unroll
            for (int j = 0; j < 4; ++j) kv[j] = *(const float4*)(&sKP[tx + 16*j][d0]);
            #pragma unroll
            for (int i = 0; i < 4; ++i)
                #pragma unroll
                for (int j = 0; j < 4; ++j)
                    s[i][j] += qv[i].x*kv[j].x + qv[i].y*kv[j].y
                             + qv[i].z*kv[j].z + qv[i].w*kv[j].w;
        }

        // ---- online softmax; rows ty+16i, the 16 tx-lanes share a row ----
        #pragma unroll
        for (int i = 0; i < 4; ++i) {
            float mx = fmaxf(fmaxf(s[i][0], s[i][1]), fmaxf(s[i][2], s[i][3]));
            #pragma unroll
            for (int off = 1; off < 16; off <<= 1)
                mx = fmaxf(mx, __shfl_xor(mx, off, 64));
            float nm = fmaxf(m_i[i], mx);
            float alpha = __expf(m_i[i] - nm);   // first tile: exp(-inf)=0
            m_i[i] = nm;
            float rs = 0.f;
            #pragma unroll
            for (int j = 0; j < 4; ++j) { s[i][j] = __expf(s[i][j] - nm); rs += s[i][j]; }
            #pragma unroll
            for (int off = 1; off < 16; off <<= 1)
                rs += __shfl_xor(rs, off, 64);
            l_i[i] = l_i[i] * alpha + rs;
            #pragma unroll
            for (int c = 0; c < 4; ++c) acc[i][c] *= alpha;
        }

        __syncthreads();   // all K reads done before overwriting sKP with P
        #pragma unroll
        for (int i = 0; i < 4; ++i)
            #pragma unroll
            for (int j = 0; j < 4; ++j)
                sKP[ty + 16*i][tx + 16*j] = s[i][j];
        __syncthreads();

        // ---- O += P @ V ----
        #pragma unroll 2
        for (int j0 = 0; j0 < BT; j0 += 4) {
            float4 pr[4], vv[4];
            #pragma unroll
            for (int i = 0; i < 4; ++i)  pr[i] = *(const float4*)(&sKP[ty + 16*i][j0]);
            #pragma unroll
            for (int jj = 0; jj < 4; ++jj) vv[jj] = *(const float4*)(&sV[j0 + jj][tx*4]);
            #pragma unroll
            for (int i = 0; i < 4; ++i) {
                acc[i][0] += pr[i].x*vv[0].x + pr[i].y*vv[1].x + pr[i].z*vv[2].x + pr[i].w*vv[3].x;
                acc[i][1] += pr[i].x*vv[0].y + pr[i].y*vv[1].y + pr[i].z*vv[2].y + pr[i].w*vv[3].y;
                acc[i][2] += pr[i].x*vv[0].z + pr[i].y*vv[1].z + pr[i].z*vv[2].z + pr[i].w*vv[3].z;
                acc[i][3] += pr[i].x*vv[0].w + pr[i].y*vv[1].w + pr[i].z*vv[2].w + pr[i].w*vv[3].w;
            }
        }
    }

    // ---- epilogue: normalize by l and store ----
    float* op = og + ((size_t)bh * SEQ + qbase) * DH;
    #pragma unroll
    for (int i = 0; i < 4; ++i) {
        int r = ty + 16 * i;
        float inv = 1.f / l_i[i];
        float4 o;
        o.x = acc[i][0]*inv; o.y = acc[i][1]*inv;
        o.z = acc[i][2]*inv; o.w = acc[i][3]*inv;
        *(float4*)(op + r * DH + tx * 4) = o;
    }
}

extern "C" void kernel_launch(void* const* d_in, const int* in_sizes, int n_in,
                              void* d_out, int out_size, void* d_ws, size_t ws_size,
                              hipStream_t stream)
{
    const float* q = (const float*)d_in[0];
    const float* k = (const float*)d_in[1];
    const float* v = (const float*)d_in[2];
    float* o = (float*)d_out;
    dim3 grid(SEQ / BT, NBH);   // 32 q-tiles x 24 batch-heads = 768 blocks
    attn_fwd<<<grid, dim3(256), 0, stream>>>(q, k, v, o);
}

// Round 2
// 257.505 us; speedup vs baseline: 1.9568x; 1.9568x over previous
//
#include <hip/hip_runtime.h>
#include <math.h>

#define SEQ   2048
#define DH    64
#define NBH   24
#define CHUNK 128               // k-cols processed per softmax update
#define NCH   (SEQ / CHUNK)     // 16
// scale * log2(e): softmax computed in exp2 domain (v_exp_f32 is 2^x)
#define QSCALE 0.18033688011112042f

typedef __attribute__((ext_vector_type(8))) short short8;
typedef __attribute__((ext_vector_type(4))) short short4v;
typedef __attribute__((ext_vector_type(4))) float f32x4;

#define MFMA(a, b, c) __builtin_amdgcn_mfma_f32_16x16x32_bf16((a), (b), (c), 0, 0, 0)

__device__ __forceinline__ short bf16rne(float f) {
    union { float f; unsigned u; } x; x.f = f;
    unsigned r = x.u + 0x7fffu + ((x.u >> 16) & 1u);
    return (short)(r >> 16);
}

// ---- pre-pass 1: Q,K fp32 -> bf16 (Q gets scale*log2e folded in) ----
__global__ void cvt_qk(const float* __restrict__ q, const float* __restrict__ k,
                       short* __restrict__ qb, short* __restrict__ kb)
{
    int idx = blockIdx.x * 256 + threadIdx.x;   // one float4-group per thread
    float4 a = ((const float4*)q)[idx];
    float4 b = ((const float4*)k)[idx];
    short4v qa, ka;
    qa[0] = bf16rne(a.x * QSCALE); qa[1] = bf16rne(a.y * QSCALE);
    qa[2] = bf16rne(a.z * QSCALE); qa[3] = bf16rne(a.w * QSCALE);
    ka[0] = bf16rne(b.x); ka[1] = bf16rne(b.y);
    ka[2] = bf16rne(b.z); ka[3] = bf16rne(b.w);
    ((short4v*)qb)[idx] = qa;
    ((short4v*)kb)[idx] = ka;
}

// ---- pre-pass 2: V fp32 [bh][s][64] -> VT bf16 [bh][64][s] via LDS tile ----
__global__ void cvt_vt(const float* __restrict__ v, short* __restrict__ vt)
{
    __shared__ short tile[64][72];   // 72-short row stride: rotating banks
    const int t  = threadIdx.x;
    const int bh = blockIdx.y;
    const int s0 = blockIdx.x * 64;

    {   // load 64(s) x 64(d) fp32 coalesced, convert, store rows to LDS
        const int sl = t >> 2, dg = (t & 3) * 16;
        const float* src = v + ((size_t)(bh * SEQ + s0 + sl)) * DH + dg;
        short8 r0, r1;
        #pragma unroll
        for (int j = 0; j < 8; ++j) {
            r0[j] = bf16rne(src[j]);
            r1[j] = bf16rne(src[8 + j]);
        }
        *(short8*)(&tile[sl][dg])     = r0;
        *(short8*)(&tile[sl][dg + 8]) = r1;
    }
    __syncthreads();
    {   // read columns, store VT rows coalesced
        const int dl = t >> 2, sg = (t & 3) * 16;
        short8 r0, r1;
        #pragma unroll
        for (int j = 0; j < 8; ++j) {
            r0[j] = tile[sg + j][dl];
            r1[j] = tile[sg + 8 + j][dl];
        }
        short* dst = vt + (size_t)bh * DH * SEQ + (size_t)dl * SEQ + s0 + sg;
        *(short8*)(dst)     = r0;
        *(short8*)(dst + 8) = r1;
    }
}

// ---- main: LDS-free, barrier-free flash attention (bf16 MFMA) ----
// Wave-independent: wave w of block (qt, bh) owns q-rows qt*64 + w*16 .. +15.
// S^T = K.Q^T (C-layout: every lane holds ONE q-row = lane&15), online softmax
// in-register, P^T -> B-frag via quad shuffles, O^T = V^T.P^T.
__global__ __launch_bounds__(256, 3)
void attn_fwd(const short* __restrict__ qb, const short* __restrict__ kb,
              const short* __restrict__ vt, float* __restrict__ og)
{
    const int lane = threadIdx.x & 63;
    const int wave = threadIdx.x >> 6;
    const int quad = lane >> 4;
    const int l16  = lane & 15;
    const int bh   = blockIdx.y;
    const int q0   = blockIdx.x * 64 + wave * 16;

    const short* qrow  = qb + ((size_t)(bh * SEQ + q0 + l16)) * DH + quad * 8;
    const short* kbase = kb + (size_t)bh * SEQ * DH;
    const short* vbase = vt + (size_t)bh * DH * SEQ;

    const short8 bq0 = *(const short8*)(qrow);        // Q^T B-frags, d 0..31
    const short8 bq1 = *(const short8*)(qrow + 32);   //               d 32..63

    f32x4 o[4];
    #pragma unroll
    for (int dt = 0; dt < 4; ++dt) o[dt] = (f32x4){0.f, 0.f, 0.f, 0.f};
    float m_i = -INFINITY, l_i = 0.f;

    #pragma unroll 1
    for (int kc = 0; kc < NCH; ++kc) {
        const int k0 = kc * CHUNK;

        // ---- S^T tiles: 8 M-tiles of 16 k-cols, K-frags straight from global
        f32x4 c[8];
        #pragma unroll
        for (int mt = 0; mt < 8; ++mt) {
            const short* krow = kbase + ((size_t)(k0 + mt * 16 + l16)) * DH + quad * 8;
            short8 ka0 = *(const short8*)(krow);
            short8 ka1 = *(const short8*)(krow + 32);
            f32x4 z = (f32x4){0.f, 0.f, 0.f, 0.f};
            z = MFMA(ka0, bq0, z);
            z = MFMA(ka1, bq1, z);
            c[mt] = z;
        }

        // ---- online softmax (exp2 domain); lane's 32 values all same q-row
        float vmax = m_i;
        #pragma unroll
        for (int mt = 0; mt < 8; ++mt)
            #pragma unroll
            for (int r = 0; r < 4; ++r) vmax = fmaxf(vmax, c[mt][r]);
        vmax = fmaxf(vmax, __shfl_xor(vmax, 16, 64));
        vmax = fmaxf(vmax, __shfl_xor(vmax, 32, 64));
        const float alpha = __builtin_amdgcn_exp2f(m_i - vmax);  // 0 on first iter
        m_i = vmax;
        float rs = 0.f;
        #pragma unroll
        for (int mt = 0; mt < 8; ++mt)
            #pragma unroll
            for (int r = 0; r < 4; ++r) {
                float p = __builtin_amdgcn_exp2f(c[mt][r] - m_i);
                c[mt][r] = p;
                rs += p;
            }
        rs += __shfl_xor(rs, 16, 64);
        rs += __shfl_xor(rs, 32, 64);
        l_i = l_i * alpha + rs;
        #pragma unroll
        for (int dt = 0; dt < 4; ++dt)
            #pragma unroll
            for (int r = 0; r < 4; ++r) o[dt][r] *= alpha;

        // ---- P^T B-frags via quad shuffles, then O^T += V^T @ P^T
        #pragma unroll
        for (int kch = 0; kch < 4; ++kch) {
            // target: lane holds P[q=l16][k0 + kch*32 + quad*8 + jj]
            short8 pf;
            #pragma unroll
            for (int jj = 0; jj < 8; ++jj) {
                const int srcLane = l16 + (((quad & 1) << 1) + (jj >> 2)) * 16;
                float v0 = __shfl(c[2 * kch][jj & 3],     srcLane, 64);
                float v1 = __shfl(c[2 * kch + 1][jj & 3], srcLane, 64);
                pf[jj] = bf16rne(quad >= 2 ? v1 : v0);
            }
            #pragma unroll
            for (int dt = 0; dt < 4; ++dt) {
                const short* vrow = vbase + ((size_t)(dt * 16 + l16)) * SEQ
                                  + k0 + kch * 32 + quad * 8;
                short8 av = *(const short8*)(vrow);   // V^T A-frag
                o[dt] = MFMA(av, pf, o[dt]);
            }
        }
    }

    // ---- epilogue: O^T C-frag (row=d, col=q-row) -> row-major store
    const float inv = 1.0f / l_i;
    float* orow = og + ((size_t)(bh * SEQ + q0 + l16)) * DH;
    #pragma unroll
    for (int dt = 0; dt < 4; ++dt) {
        f32x4 st;
        #pragma unroll
        for (int r = 0; r < 4; ++r) st[r] = o[dt][r] * inv;
        *(f32x4*)(orow + dt * 16 + quad * 4) = st;
    }
}

extern "C" void kernel_launch(void* const* d_in, const int* in_sizes, int n_in,
                              void* d_out, int out_size, void* d_ws, size_t ws_size,
                              hipStream_t stream)
{
    const float* q = (const float*)d_in[0];
    const float* k = (const float*)d_in[1];
    const float* v = (const float*)d_in[2];
    float* o = (float*)d_out;

    const size_t nelem = (size_t)NBH * SEQ * DH;          // 3,145,728
    short* qb = (short*)d_ws;                              // 6.29 MB
    short* kb = qb + nelem;                                // 6.29 MB
    short* vtp = kb + nelem;                               // 6.29 MB (18.9 MB total)

    cvt_qk<<<nelem / 4 / 256, 256, 0, stream>>>(q, k, qb, kb);
    cvt_vt<<<dim3(SEQ / 64, NBH), 256, 0, stream>>>(v, vtp);
    attn_fwd<<<dim3(SEQ / 64, NBH), 256, 0, stream>>>(qb, kb, vtp, o);
}